// Round 1
// baseline (319.775 us; speedup 1.0000x reference)
//
#include <hip/hip_runtime.h>

#define NEGV (-1e30f)

// ---------------------------------------------------------------------------
// Kernel 1: channel-mean (over C=256) + corner mask -> scores (n, H*W)
// Block: 256 threads = 8 channel-groups (32ch) x 32 position-quads (4 pos).
// Grid: QUADS blocks (covers 32 batches * QUADS quad-tasks).
// ---------------------------------------------------------------------------
template <int H, int W, int R0, int R1>
__global__ __launch_bounds__(256) void mean_mask_kernel(const float* __restrict__ x,
                                                        float* __restrict__ scores) {
    constexpr int HW = H * W;
    constexpr int QUADS = HW / 4;         // HW % 4 == 0 for 3136/784/196
    const int tid = threadIdx.x;
    const int cg = tid >> 5;              // channel group 0..7 (32 channels each)
    const int pl = tid & 31;              // quad lane 0..31
    const int q = blockIdx.x * 32 + pl;   // global quad task, in [0, 32*QUADS)

    __shared__ float4 part[256];

    float4 acc = make_float4(0.f, 0.f, 0.f, 0.f);
    if (q < 32 * QUADS) {
        const int b = q / QUADS;
        const int quad = q - b * QUADS;
        const float* base = x + (size_t)b * 256 * HW + (size_t)cg * 32 * HW + quad * 4;
#pragma unroll 8
        for (int c = 0; c < 32; ++c) {
            const float4 v = *reinterpret_cast<const float4*>(base + (size_t)c * HW);
            acc.x += v.x; acc.y += v.y; acc.z += v.z; acc.w += v.w;
        }
    }
    part[tid] = acc;
    __syncthreads();

    if (tid < 32 && q < 32 * QUADS) {
        float4 s = part[pl];
#pragma unroll
        for (int g = 1; g < 8; ++g) {
            const float4 v = part[g * 32 + pl];
            s.x += v.x; s.y += v.y; s.z += v.z; s.w += v.w;
        }
        const int b = q / QUADS;
        const int quad = q - b * QUADS;
        const int p0 = quad * 4;
        float r[4] = {s.x, s.y, s.z, s.w};
        float o[4];
#pragma unroll
        for (int e = 0; e < 4; ++e) {
            const int p = p0 + e;
            const int y = p / W;
            const int xx = p - y * W;
            const float val = r[e] * (1.0f / 256.0f);
            const bool in = (y >= R0) && (y < R1) && (xx >= R0) && (xx < R1);
            o[e] = in ? val : 0.0f;
        }
        *reinterpret_cast<float4*>(scores + (size_t)b * HW + p0) =
            make_float4(o[0], o[1], o[2], o[3]);
    }
}

// ---------------------------------------------------------------------------
// Kernel 2: greedy NMS top-k. One block per (scale, batch): 96 blocks.
// blocks 0..31 -> scale3 (56x56, topk5), 32..63 -> scale4, 64..95 -> scale5.
// ---------------------------------------------------------------------------
__global__ __launch_bounds__(256) void nms_kernel(const float* __restrict__ sc3,
                                                  const float* __restrict__ sc4,
                                                  const float* __restrict__ sc5,
                                                  float* __restrict__ out) {
    __shared__ float s[3136];
    __shared__ float red_v[256];
    __shared__ int red_i[256];

    const int blk = blockIdx.x;
    const int sid = blk >> 5;
    const int b = blk & 31;

    int HW, Wd, topk;
    float stride, size_;
    const float* sc;
    float* o;
    if (sid == 0) {
        HW = 3136; Wd = 56; topk = 5; stride = 8.f;  size_ = 64.f;
        sc = sc3 + (size_t)b * 3136; o = out + (size_t)(b * 5) * 5;
    } else if (sid == 1) {
        HW = 784;  Wd = 28; topk = 3; stride = 16.f; size_ = 128.f;
        sc = sc4 + (size_t)b * 784;  o = out + 800 + (size_t)(b * 3) * 5;
    } else {
        HW = 196;  Wd = 14; topk = 1; stride = 32.f; size_ = 256.f;
        sc = sc5 + (size_t)b * 196;  o = out + 1280 + (size_t)b * 5;
    }

    const int tid = threadIdx.x;

    // Load scores into LDS; accumulate sum for mean.
    float acc = 0.f;
    for (int j = tid; j < HW; j += 256) {
        const float v = sc[j];
        s[j] = v;
        acc += v;
    }
    red_v[tid] = acc;
    __syncthreads();
    for (int off = 128; off > 0; off >>= 1) {
        if (tid < off) red_v[tid] += red_v[tid + off];
        __syncthreads();
    }
    const float mean = red_v[0] / (float)HW;
    __syncthreads();

    // valid = score > mean; else NEG
    for (int j = tid; j < HW; j += 256) {
        const float v = s[j];
        s[j] = (v > mean) ? v : NEGV;
    }
    __syncthreads();

    const float half = 0.5f * size_;
    const float area2 = 2.0f * size_ * size_;  // a1 + a2

    for (int k = 0; k < topk; ++k) {
        // Block-wide argmax with first-index tie-break (matches jnp.argmax).
        float bv = -3.0e38f;
        int bi = 0x7fffffff;
        for (int j = tid; j < HW; j += 256) {
            const float v = s[j];
            if (v > bv) { bv = v; bi = j; }   // ascending j -> min index kept
        }
        red_v[tid] = bv;
        red_i[tid] = bi;
        __syncthreads();
        for (int off = 128; off > 0; off >>= 1) {
            if (tid < off) {
                const float v2 = red_v[tid + off];
                const int i2 = red_i[tid + off];
                const float v1 = red_v[tid];
                const int i1 = red_i[tid];
                if (v2 > v1 || (v2 == v1 && i2 < i1)) {
                    red_v[tid] = v2;
                    red_i[tid] = i2;
                }
            }
            __syncthreads();
        }
        const int idx = red_i[0];

        const int gy = idx / Wd;
        const int gx = idx - gy * Wd;
        const float cx = (float)gx * stride;
        const float cy = (float)gy * stride;
        const float bx1 = cx - half, by1 = cy - half;
        const float bx2 = cx + half, by2 = cy + half;

        if (tid == 0) {
            float* r = o + (size_t)k * 5;
            r[0] = (float)b;
            r[1] = fmaxf(bx1, 0.f);
            r[2] = fmaxf(by1, 0.f);
            r[3] = fminf(bx2, 447.f);   // IMG_W - 1
            r[4] = fminf(by2, 447.f);   // IMG_H - 1
        }

        // Suppress: IoU on raw (unclamped) anchors, threshold 0.05.
        for (int j = tid; j < HW; j += 256) {
            const int ay = j / Wd;
            const int ax = j - ay * Wd;
            const float acx = (float)ax * stride;
            const float acy = (float)ay * stride;
            const float ix1 = fmaxf(bx1, acx - half);
            const float iy1 = fmaxf(by1, acy - half);
            const float ix2 = fminf(bx2, acx + half);
            const float iy2 = fminf(by2, acy + half);
            const float inter = fmaxf(ix2 - ix1, 0.f) * fmaxf(iy2 - iy1, 0.f);
            const float iou = inter / (area2 - inter);
            if (iou > 0.05f || j == idx) s[j] = NEGV;
        }
        __syncthreads();
    }
}

// ---------------------------------------------------------------------------
// Kernel 3: per-batch union bounds of the 9 boxes -> (x1i, y1i, cw, ch) ints
// ---------------------------------------------------------------------------
__global__ void bounds_kernel(const float* __restrict__ out, int* __restrict__ bnds) {
    const int b = threadIdx.x;
    if (b >= 32) return;
    float x1 = 3.0e38f, y1 = 3.0e38f, x2 = -3.0e38f, y2 = -3.0e38f;
#pragma unroll
    for (int k = 0; k < 5; ++k) {
        const float* r = out + (size_t)(b * 5 + k) * 5;
        x1 = fminf(x1, r[1]); y1 = fminf(y1, r[2]);
        x2 = fmaxf(x2, r[3]); y2 = fmaxf(y2, r[4]);
    }
#pragma unroll
    for (int k = 0; k < 3; ++k) {
        const float* r = out + 800 + (size_t)(b * 3 + k) * 5;
        x1 = fminf(x1, r[1]); y1 = fminf(y1, r[2]);
        x2 = fmaxf(x2, r[3]); y2 = fmaxf(y2, r[4]);
    }
    {
        const float* r = out + 1280 + (size_t)b * 5;
        x1 = fminf(x1, r[1]); y1 = fminf(y1, r[2]);
        x2 = fmaxf(x2, r[3]); y2 = fmaxf(y2, r[4]);
    }
    const int x1i = (int)floorf(x1 * 0.125f);
    const int y1i = (int)floorf(y1 * 0.125f);
    const int x2i = (int)floorf(x2 * 0.125f);
    const int y2i = (int)floorf(y2 * 0.125f);
    bnds[b * 4 + 0] = x1i;
    bnds[b * 4 + 1] = y1i;
    bnds[b * 4 + 2] = x2i - x1i;  // cw
    bnds[b * 4 + 3] = y2i - y1i;  // ch
}

// ---------------------------------------------------------------------------
// Kernel 4: bilinear crop-resize of x2 -> (32, 256, 56, 56).
// One block per (b, c) plane: 8192 blocks x 256 threads.
// ---------------------------------------------------------------------------
__global__ __launch_bounds__(256) void crop_kernel(const float* __restrict__ x2,
                                                   const int* __restrict__ bnds,
                                                   float* __restrict__ out) {
    const int bc = blockIdx.x;   // b*256 + c
    const int b = bc >> 8;
    const int tid = threadIdx.x;

    const int x1i = bnds[b * 4 + 0];
    const int y1i = bnds[b * 4 + 1];
    const int cw = bnds[b * 4 + 2];
    const int ch = bnds[b * 4 + 3];
    const float sxs = (float)cw / 56.0f;
    const float sys = (float)ch / 56.0f;

    const float* plane = x2 + (size_t)bc * 3136;
    float* op = out + (size_t)bc * 3136;

    for (int p = tid; p < 3136; p += 256) {
        const int y = p / 56;
        const int xx = p - y * 56;
        const float sy = fmaxf((y + 0.5f) * sys - 0.5f, 0.f);
        const float sx = fmaxf((xx + 0.5f) * sxs - 0.5f, 0.f);
        const int iy0 = (int)sy;         // floor (sy >= 0)
        const int ix0 = (int)sx;
        const float fy = sy - (float)iy0;
        const float fx = sx - (float)ix0;
        const int iy1 = min(iy0 + 1, ch - 1);
        const int ix1 = min(ix0 + 1, cw - 1);
        const int gy0 = (y1i + iy0) * 56;
        const int gy1 = (y1i + iy1) * 56;
        const int gx0 = x1i + ix0;
        const int gx1 = x1i + ix1;
        const float v00 = plane[gy0 + gx0];
        const float v01 = plane[gy0 + gx1];
        const float v10 = plane[gy1 + gx0];
        const float v11 = plane[gy1 + gx1];
        const float top = v00 + fx * (v01 - v00);
        const float bot = v10 + fx * (v11 - v10);
        op[p] = top + fy * (bot - top);
    }
}

// ---------------------------------------------------------------------------
extern "C" void kernel_launch(void* const* d_in, const int* in_sizes, int n_in,
                              void* d_out, int out_size, void* d_ws, size_t ws_size,
                              hipStream_t stream) {
    const float* x2 = (const float*)d_in[0];
    const float* x3 = (const float*)d_in[1];
    const float* x4 = (const float*)d_in[2];
    const float* x5 = (const float*)d_in[3];
    float* out = (float*)d_out;

    float* sc3 = (float*)d_ws;                 // 32*3136 floats
    float* sc4 = sc3 + 32 * 3136;              // 32*784
    float* sc5 = sc4 + 32 * 784;               // 32*196
    int* bnds = (int*)(sc5 + 32 * 196);        // 32*4 ints

    // scores: channel mean + corner mask. Mask rows/cols [int(0.1h), int(0.9h)).
    mean_mask_kernel<56, 56, 5, 50><<<784, 256, 0, stream>>>(x3, sc3);
    mean_mask_kernel<28, 28, 2, 25><<<196, 256, 0, stream>>>(x4, sc4);
    mean_mask_kernel<14, 14, 1, 12><<<49, 256, 0, stream>>>(x5, sc5);

    // greedy NMS top-k for all scales (96 independent problems)
    nms_kernel<<<96, 256, 0, stream>>>(sc3, sc4, sc5, out);

    // per-batch union bounds
    bounds_kernel<<<1, 64, 0, stream>>>(out, bnds);

    // bilinear crop-resize of x2
    crop_kernel<<<8192, 256, 0, stream>>>(x2, bnds, out + 1440);
}

// Round 3
// 291.695 us; speedup vs baseline: 1.0963x; 1.0963x over previous
//
#include <hip/hip_runtime.h>

#define NEGV (-1e30f)

// ---------------------------------------------------------------------------
// Kernel 1: fused channel-mean (C=256) + corner mask for all three scales.
// Block: 256 threads = 8 channel-groups (32ch) x 32 position-quads (4 pos).
// Grid: 784 (scale3) + 196 (scale4) + 49 (scale5) = 1029 blocks.
// ---------------------------------------------------------------------------
template <int H, int W, int R0, int R1>
__device__ __forceinline__ void mean_body(int blk, const float* __restrict__ x,
                                          float* __restrict__ scores,
                                          float4* part) {
    constexpr int HW = H * W;
    constexpr int QUADS = HW / 4;
    const int tid = threadIdx.x;
    const int cg = tid >> 5;              // channel group 0..7 (32 channels each)
    const int pl = tid & 31;              // quad lane 0..31
    const int q = blk * 32 + pl;          // global quad task (grid sized exactly)

    const int b = q / QUADS;
    const int quad = q - b * QUADS;
    const float* base = x + (size_t)b * 256 * HW + (size_t)cg * 32 * HW + quad * 4;

    float4 acc = make_float4(0.f, 0.f, 0.f, 0.f);
#pragma unroll 8
    for (int c = 0; c < 32; ++c) {
        const float4 v = *reinterpret_cast<const float4*>(base + (size_t)c * HW);
        acc.x += v.x; acc.y += v.y; acc.z += v.z; acc.w += v.w;
    }
    part[tid] = acc;
    __syncthreads();

    if (tid < 32) {
        float4 s = part[pl];
#pragma unroll
        for (int g = 1; g < 8; ++g) {
            const float4 v = part[g * 32 + pl];
            s.x += v.x; s.y += v.y; s.z += v.z; s.w += v.w;
        }
        const int p0 = quad * 4;
        float r[4] = {s.x, s.y, s.z, s.w};
        float o[4];
#pragma unroll
        for (int e = 0; e < 4; ++e) {
            const int p = p0 + e;
            const int y = p / W;
            const int xx = p - y * W;
            const float val = r[e] * (1.0f / 256.0f);
            const bool in = (y >= R0) && (y < R1) && (xx >= R0) && (xx < R1);
            o[e] = in ? val : 0.0f;
        }
        *reinterpret_cast<float4*>(scores + (size_t)b * HW + p0) =
            make_float4(o[0], o[1], o[2], o[3]);
    }
}

__global__ __launch_bounds__(256) void mean_all_kernel(const float* __restrict__ x3,
                                                       const float* __restrict__ x4,
                                                       const float* __restrict__ x5,
                                                       float* __restrict__ sc3,
                                                       float* __restrict__ sc4,
                                                       float* __restrict__ sc5) {
    __shared__ float4 part[256];
    const int bid = blockIdx.x;
    if (bid < 784) {
        mean_body<56, 56, 5, 50>(bid, x3, sc3, part);
    } else if (bid < 980) {
        mean_body<28, 28, 2, 25>(bid - 784, x4, sc4, part);
    } else {
        mean_body<14, 14, 1, 12>(bid - 980, x5, sc5, part);
    }
}

// ---------------------------------------------------------------------------
// Kernel 2: greedy NMS top-k, register-resident scores.
// One block per (scale, batch): 96 blocks x 256 threads.
// Argmax: per-thread scan (regs) -> 64-wide shfl butterfly -> 4-entry LDS.
// Tie-break: strictly-greater + min index == jnp.argmax first-occurrence.
// ---------------------------------------------------------------------------
template <int HW, int W, int TOPK, int ISTRIDE, int ISIZE>
__device__ __forceinline__ void nms_body(int b, const float* __restrict__ sc,
                                         float* __restrict__ o,
                                         float* rv, int* ri, float* rs) {
    constexpr int NPT = (HW + 255) / 256;
    const int tid = threadIdx.x;
    const int lane = tid & 63;
    const int wave = tid >> 6;

    float s[NPT];
    float sum = 0.f;
#pragma unroll
    for (int i = 0; i < NPT; ++i) {
        const int j = tid + 256 * i;
        const float v = (j < HW) ? sc[j] : NEGV;
        s[i] = v;
        if (j < HW) sum += v;
    }
    // block sum -> mean
#pragma unroll
    for (int off = 32; off > 0; off >>= 1) sum += __shfl_down(sum, off, 64);
    if (lane == 0) rs[wave] = sum;
    __syncthreads();
    const float mean = (rs[0] + rs[1] + rs[2] + rs[3]) / (float)HW;

#pragma unroll
    for (int i = 0; i < NPT; ++i) s[i] = (s[i] > mean) ? s[i] : NEGV;

    constexpr float half = 0.5f * (float)ISIZE;
    constexpr float area2 = 2.0f * (float)ISIZE * (float)ISIZE;

    for (int k = 0; k < TOPK; ++k) {
        float bv = -3.0e38f;
        int bi = 0x7fffffff;
#pragma unroll
        for (int i = 0; i < NPT; ++i) {
            if (s[i] > bv) { bv = s[i]; bi = tid + 256 * i; }
        }
#pragma unroll
        for (int off = 32; off > 0; off >>= 1) {
            const float ov = __shfl_down(bv, off, 64);
            const int oi = __shfl_down(bi, off, 64);
            if (ov > bv || (ov == bv && oi < bi)) { bv = ov; bi = oi; }
        }
        if (lane == 0) { rv[wave] = bv; ri[wave] = bi; }
        __syncthreads();
        float wv = rv[0];
        int wi = ri[0];
#pragma unroll
        for (int w = 1; w < 4; ++w) {
            const float v2 = rv[w];
            const int i2 = ri[w];
            if (v2 > wv || (v2 == wv && i2 < wi)) { wv = v2; wi = i2; }
        }
        __syncthreads();  // WAR: protect rv/ri before next iteration's writes

        const int gy = wi / W;
        const int gx = wi - gy * W;
        const float bx1 = (float)gx * (float)ISTRIDE - half;
        const float by1 = (float)gy * (float)ISTRIDE - half;
        const float bx2 = (float)gx * (float)ISTRIDE + half;
        const float by2 = (float)gy * (float)ISTRIDE + half;

        if (tid == 0) {
            float* r = o + k * 5;
            r[0] = (float)b;
            r[1] = fmaxf(bx1, 0.f);
            r[2] = fmaxf(by1, 0.f);
            r[3] = fminf(bx2, 447.f);
            r[4] = fminf(by2, 447.f);
        }

        // Suppress: IoU on raw (unclamped) anchors, threshold 0.05.
#pragma unroll
        for (int i = 0; i < NPT; ++i) {
            const int j = tid + 256 * i;
            const int ay = j / W;
            const int ax = j - ay * W;
            const float acx = (float)ax * (float)ISTRIDE;
            const float acy = (float)ay * (float)ISTRIDE;
            const float ix1 = fmaxf(bx1, acx - half);
            const float iy1 = fmaxf(by1, acy - half);
            const float ix2 = fminf(bx2, acx + half);
            const float iy2 = fminf(by2, acy + half);
            const float inter = fmaxf(ix2 - ix1, 0.f) * fmaxf(iy2 - iy1, 0.f);
            const float iou = inter / (area2 - inter);
            if (iou > 0.05f || j == wi) s[i] = NEGV;
        }
    }
}

__global__ __launch_bounds__(256) void nms_kernel(const float* __restrict__ sc3,
                                                  const float* __restrict__ sc4,
                                                  const float* __restrict__ sc5,
                                                  float* __restrict__ out) {
    __shared__ float rv[4];
    __shared__ int ri[4];
    __shared__ float rs[4];
    const int blk = blockIdx.x;
    const int sid = blk >> 5;
    const int b = blk & 31;
    if (sid == 0) {
        nms_body<3136, 56, 5, 8, 64>(b, sc3 + (size_t)b * 3136, out + (size_t)b * 25, rv, ri, rs);
    } else if (sid == 1) {
        nms_body<784, 28, 3, 16, 128>(b, sc4 + (size_t)b * 784, out + 800 + (size_t)b * 15, rv, ri, rs);
    } else {
        nms_body<196, 14, 1, 32, 256>(b, sc5 + (size_t)b * 196, out + 1280 + (size_t)b * 5, rv, ri, rs);
    }
}

// ---------------------------------------------------------------------------
// Kernel 3: per-batch union bounds + bilinear axis tables (1 block, 256 thr).
// ty0/ty1 are pre-multiplied row offsets ((y1i+i)*56); tx0/tx1 are columns.
// ---------------------------------------------------------------------------
__global__ __launch_bounds__(256) void tables_kernel(const float* __restrict__ out,
                                                     int* __restrict__ ty0, int* __restrict__ ty1,
                                                     float* __restrict__ tfy,
                                                     int* __restrict__ tx0, int* __restrict__ tx1,
                                                     float* __restrict__ tfx) {
    __shared__ int sx1i[32], sy1i[32], scw[32], sch[32];
    const int tid = threadIdx.x;
    if (tid < 32) {
        const int b = tid;
        float x1 = 3.0e38f, y1 = 3.0e38f, x2 = -3.0e38f, y2 = -3.0e38f;
#pragma unroll
        for (int k = 0; k < 5; ++k) {
            const float* r = out + (size_t)(b * 5 + k) * 5;
            x1 = fminf(x1, r[1]); y1 = fminf(y1, r[2]);
            x2 = fmaxf(x2, r[3]); y2 = fmaxf(y2, r[4]);
        }
#pragma unroll
        for (int k = 0; k < 3; ++k) {
            const float* r = out + 800 + (size_t)(b * 3 + k) * 5;
            x1 = fminf(x1, r[1]); y1 = fminf(y1, r[2]);
            x2 = fmaxf(x2, r[3]); y2 = fmaxf(y2, r[4]);
        }
        {
            const float* r = out + 1280 + (size_t)b * 5;
            x1 = fminf(x1, r[1]); y1 = fminf(y1, r[2]);
            x2 = fmaxf(x2, r[3]); y2 = fmaxf(y2, r[4]);
        }
        const int x1i = (int)floorf(x1 * 0.125f);
        const int y1i = (int)floorf(y1 * 0.125f);
        const int x2i = (int)floorf(x2 * 0.125f);
        const int y2i = (int)floorf(y2 * 0.125f);
        sx1i[b] = x1i; sy1i[b] = y1i;
        scw[b] = x2i - x1i; sch[b] = y2i - y1i;
    }
    __syncthreads();

    for (int t = tid; t < 3584; t += 256) {
        const int b = t / 112;
        const int r = t - b * 112;
        const int axis = r / 56;
        const int o = r - axis * 56;
        if (axis == 0) {
            const int clen = sch[b];
            const int start = sy1i[b];
            const float s = fmaxf(((float)o + 0.5f) * ((float)clen / 56.0f) - 0.5f, 0.f);
            const int i0 = (int)s;
            const int i1 = min(i0 + 1, clen - 1);
            ty0[b * 56 + o] = (start + i0) * 56;
            ty1[b * 56 + o] = (start + i1) * 56;
            tfy[b * 56 + o] = s - (float)i0;
        } else {
            const int clen = scw[b];
            const int start = sx1i[b];
            const float s = fmaxf(((float)o + 0.5f) * ((float)clen / 56.0f) - 0.5f, 0.f);
            const int i0 = (int)s;
            const int i1 = min(i0 + 1, clen - 1);
            tx0[b * 56 + o] = start + i0;
            tx1[b * 56 + o] = start + i1;
            tfx[b * 56 + o] = s - (float)i0;
        }
    }
}

// ---------------------------------------------------------------------------
// Kernel 4: bilinear crop-resize, table-driven. One block per (b,c) plane.
// 448 threads: p = tid + 448*i, 448 = 8*56 so xx = tid%56 is loop-invariant
// and y = tid/56 + 8*i. Stores are block-contiguous; x-params hoisted.
// ---------------------------------------------------------------------------
__global__ __launch_bounds__(448) void crop_kernel(const float* __restrict__ x2,
                                                   const int* __restrict__ ty0,
                                                   const int* __restrict__ ty1,
                                                   const float* __restrict__ tfy,
                                                   const int* __restrict__ tx0,
                                                   const int* __restrict__ tx1,
                                                   const float* __restrict__ tfx,
                                                   float* __restrict__ outc) {
    __shared__ int sy0[56], sy1[56];
    __shared__ float sfy[56];
    __shared__ int sx0[56], sx1[56];
    __shared__ float sfx[56];

    const int bc = blockIdx.x;  // b*256 + c
    const int b = bc >> 8;
    const int tid = threadIdx.x;

    // One coalesced pass: 6 tables x 56 entries = 336 loads.
    if (tid < 336) {
        const int a = tid / 56;      // which table
        const int o = tid - a * 56;  // entry
        const int gi = b * 56 + o;
        switch (a) {
            case 0: sy0[o] = ty0[gi]; break;
            case 1: sy1[o] = ty1[gi]; break;
            case 2: sfy[o] = tfy[gi]; break;
            case 3: sx0[o] = tx0[gi]; break;
            case 4: sx1[o] = tx1[gi]; break;
            default: sfx[o] = tfx[gi]; break;
        }
    }
    __syncthreads();

    const int y0 = tid / 56;       // 0..7
    const int xx = tid - y0 * 56;  // 0..55, loop-invariant
    const int gx0 = sx0[xx];
    const int gx1 = sx1[xx];
    const float fx = sfx[xx];

    const float* plane = x2 + (size_t)bc * 3136;
    float* op = outc + (size_t)bc * 3136;

#pragma unroll
    for (int i = 0; i < 7; ++i) {
        const int y = y0 + 8 * i;
        const int r0 = sy0[y];
        const int r1 = sy1[y];
        const float fy = sfy[y];
        const float v00 = plane[r0 + gx0];
        const float v01 = plane[r0 + gx1];
        const float v10 = plane[r1 + gx0];
        const float v11 = plane[r1 + gx1];
        const float top = v00 + fx * (v01 - v00);
        const float bot = v10 + fx * (v11 - v10);
        op[tid + 448 * i] = top + fy * (bot - top);
    }
}

// ---------------------------------------------------------------------------
extern "C" void kernel_launch(void* const* d_in, const int* in_sizes, int n_in,
                              void* d_out, int out_size, void* d_ws, size_t ws_size,
                              hipStream_t stream) {
    const float* x2 = (const float*)d_in[0];
    const float* x3 = (const float*)d_in[1];
    const float* x4 = (const float*)d_in[2];
    const float* x5 = (const float*)d_in[3];
    float* out = (float*)d_out;

    float* sc3 = (float*)d_ws;                 // 32*3136
    float* sc4 = sc3 + 32 * 3136;              // 32*784
    float* sc5 = sc4 + 32 * 784;               // 32*196
    int* ty0 = (int*)(sc5 + 32 * 196);         // 32*56 each below
    int* ty1 = ty0 + 32 * 56;
    int* tx0 = ty1 + 32 * 56;
    int* tx1 = tx0 + 32 * 56;
    float* tfy = (float*)(tx1 + 32 * 56);
    float* tfx = tfy + 32 * 56;

    mean_all_kernel<<<1029, 256, 0, stream>>>(x3, x4, x5, sc3, sc4, sc5);
    nms_kernel<<<96, 256, 0, stream>>>(sc3, sc4, sc5, out);
    tables_kernel<<<1, 256, 0, stream>>>(out, ty0, ty1, tfy, tx0, tx1, tfx);
    crop_kernel<<<8192, 448, 0, stream>>>(x2, ty0, ty1, tfy, tx0, tx1, tfx, out + 1440);
}